// Round 1
// baseline (941.796 us; speedup 1.0000x reference)
//
#include <hip/hip_runtime.h>

typedef _Float16 f16x8 __attribute__((ext_vector_type(8)));
typedef _Float16 f16x4 __attribute__((ext_vector_type(4)));
typedef float fx4 __attribute__((ext_vector_type(4)));

static constexpr int S_LEN = 2048;
static constexpr int BATCH = 2;
static constexpr int TOKENS = BATCH * S_LEN;   // 4096
static constexpr int DIM = 2048;
static constexpr int NH = 16;
static constexpr int QR = 1536;
static constexpr int KVR = 512;
static constexpr int DN = 128;
static constexpr int DR = 64;
static constexpr int DV = 128;

// ---------------- f32 -> f16 conversion ----------------
__global__ void cvt_f32_f16(const float* __restrict__ in, _Float16* __restrict__ out, int n4) {
  int i = blockIdx.x * 256 + threadIdx.x;
  if (i >= n4) return;
  fx4 v = *(const fx4*)(in + (size_t)i * 4);
  f16x4 o;
  o[0] = (_Float16)v[0]; o[1] = (_Float16)v[1];
  o[2] = (_Float16)v[2]; o[3] = (_Float16)v[3];
  *(f16x4*)(out + (size_t)i * 4) = o;
}

// ---------------- NT GEMM: C[M,N] = A[M,K] * W[N,K]^T, f16 in, fp32 acc ----
// 128x128 tile, BK=32, 4 waves (2x2), each wave 4x4 MFMA tiles of 16x16x32.
// LDS rows padded 32->40 halves (80B stride: 16B-aligned, conflict-free-ish).
// M must be a multiple of 128 (true for all calls: M=4096). N guarded.
template <typename OutT>
__global__ __launch_bounds__(256) void gemm_nt(const _Float16* __restrict__ A,
                                               const _Float16* __restrict__ W,
                                               OutT* __restrict__ C,
                                               int M, int N, int K) {
  __shared__ __attribute__((aligned(16))) _Float16 As[128][40];
  __shared__ __attribute__((aligned(16))) _Float16 Ws[128][40];
  const int tid = threadIdx.x;
  const int lane = tid & 63;
  const int wave = tid >> 6;
  const int wr = (wave >> 1) * 64;   // wave row offset in tile
  const int wc = (wave & 1) * 64;    // wave col offset in tile
  const int m16 = lane & 15;
  const int quad = lane >> 4;
  const int m0 = blockIdx.y * 128;
  const int n0 = blockIdx.x * 128;

  const fx4 fz = {0.f, 0.f, 0.f, 0.f};
  fx4 acc[4][4];
#pragma unroll
  for (int i = 0; i < 4; ++i)
#pragma unroll
    for (int j = 0; j < 4; ++j) acc[i][j] = fz;

  for (int k0 = 0; k0 < K; k0 += 32) {
#pragma unroll
    for (int it = 0; it < 2; ++it) {
      const int chunk = it * 256 + tid;     // 0..511
      const int r = chunk >> 2;             // 0..127
      const int kc = (chunk & 3) * 8;       // 0,8,16,24
      f16x8 av = *(const f16x8*)(A + (size_t)(m0 + r) * K + k0 + kc);
      *(f16x8*)(&As[r][kc]) = av;
      f16x8 wv;
      const int wrow = n0 + r;
      if (wrow < N) {
        wv = *(const f16x8*)(W + (size_t)wrow * K + k0 + kc);
      } else {
#pragma unroll
        for (int z = 0; z < 8; ++z) wv[z] = (_Float16)0.f;
      }
      *(f16x8*)(&Ws[r][kc]) = wv;
    }
    __syncthreads();
    f16x8 af[4], wf[4];
#pragma unroll
    for (int i = 0; i < 4; ++i)
      af[i] = *(const f16x8*)(&As[wr + i * 16 + m16][quad * 8]);
#pragma unroll
    for (int j = 0; j < 4; ++j)
      wf[j] = *(const f16x8*)(&Ws[wc + j * 16 + m16][quad * 8]);
#pragma unroll
    for (int i = 0; i < 4; ++i)
#pragma unroll
      for (int j = 0; j < 4; ++j)
        acc[i][j] = __builtin_amdgcn_mfma_f32_16x16x32_f16(af[i], wf[j], acc[i][j], 0, 0, 0);
    __syncthreads();
  }

#pragma unroll
  for (int i = 0; i < 4; ++i) {
#pragma unroll
    for (int j = 0; j < 4; ++j) {
      const int col = n0 + wc + j * 16 + m16;
      if (col < N) {
#pragma unroll
        for (int r = 0; r < 4; ++r) {
          const int row = m0 + wr + i * 16 + quad * 4 + r;
          C[(size_t)row * N + col] = (OutT)acc[i][j][r];
        }
      }
    }
  }
}

// ---------------- in-place RMSNorm over f16 rows (fp32 math) ---------------
template <int NC>
__global__ __launch_bounds__(256) void rmsnorm_ip(_Float16* __restrict__ xx,
                                                  const float* __restrict__ w) {
  const int row = blockIdx.x;
  _Float16* p = xx + (size_t)row * NC;
  float ss = 0.f;
  for (int c = threadIdx.x; c < NC; c += 256) {
    const float v = (float)p[c];
    ss += v * v;
  }
#pragma unroll
  for (int d = 1; d < 64; d <<= 1) ss += __shfl_xor(ss, d);
  __shared__ float red[4];
  if ((threadIdx.x & 63) == 0) red[threadIdx.x >> 6] = ss;
  __syncthreads();
  const float rs = rsqrtf((red[0] + red[1] + red[2] + red[3]) * (1.0f / NC) + 1e-6f);
  for (int c = threadIdx.x; c < NC; c += 256)
    p[c] = (_Float16)((float)p[c] * rs * w[c]);
}

// ---------------- in-place RoPE (LLaMA interleaved pairs, d=64) ------------
__global__ void rope_q(_Float16* __restrict__ qpe) {  // [T, NH*64]
  const int idx = blockIdx.x * 256 + threadIdx.x;     // T*NH*32 threads
  const int t = idx >> 9;
  const int rem = idx & 511;
  const int hh = rem >> 5;
  const int i = rem & 31;
  const int s = t & (S_LEN - 1);
  const float fr = powf(10000.0f, -(float)i * (1.0f / 32.0f));
  const float ang = (float)s * fr;
  const float sn = sinf(ang), cs = cosf(ang);
  const size_t base = (size_t)t * (NH * DR) + hh * DR + 2 * i;
  const float x1 = (float)qpe[base];
  const float x2 = (float)qpe[base + 1];
  qpe[base] = (_Float16)(x1 * cs - x2 * sn);
  qpe[base + 1] = (_Float16)(x1 * sn + x2 * cs);
}

__global__ void rope_k(_Float16* __restrict__ kr) {  // [T, 64]
  const int idx = blockIdx.x * 256 + threadIdx.x;    // T*32 threads
  const int t = idx >> 5;
  const int i = idx & 31;
  const int s = t & (S_LEN - 1);
  const float fr = powf(10000.0f, -(float)i * (1.0f / 32.0f));
  const float ang = (float)s * fr;
  const float sn = sinf(ang), cs = cosf(ang);
  const size_t base = (size_t)t * DR + 2 * i;
  const float x1 = (float)kr[base];
  const float x2 = (float)kr[base + 1];
  kr[base] = (_Float16)(x1 * cs - x2 * sn);
  kr[base + 1] = (_Float16)(x1 * sn + x2 * cs);
}

// ---------------- causal flash attention (MFMA) ----------------------------
// Block: 256 thr = 4 waves; each wave owns 16 q-rows (block = 64 q-rows).
// K-tiles of 32 keys staged in LDS; online softmax in MFMA C/D layout;
// P -> LDS -> A-layout; V^T in LDS so PV B-frags are contiguous 16B reads.
__global__ __launch_bounds__(256) void mla_attention(
    const _Float16* __restrict__ q_nope,  // [T, NH*128]
    const _Float16* __restrict__ q_pe,    // [T, NH*64]  (roped)
    const _Float16* __restrict__ kv_up,   // [T, NH*256] (k_nope | v)
    const _Float16* __restrict__ k_rope,  // [T, 64]     (roped)
    _Float16* __restrict__ out)           // [T, NH*128]
{
  __shared__ __attribute__((aligned(16))) _Float16 Qs[64][200];
  __shared__ __attribute__((aligned(16))) _Float16 Ks[32][200];
  __shared__ __attribute__((aligned(16))) _Float16 Vt[128][40];
  __shared__ __attribute__((aligned(16))) _Float16 Ps[4][16][32];

  // longest-running (latest) q-blocks first for load balance
  const int qb = (gridDim.x - 1 - blockIdx.x) * 64;
  const int h = blockIdx.y;
  const int b = blockIdx.z;
  const int tid = threadIdx.x;
  const int lane = tid & 63;
  const int wave = tid >> 6;
  const int m16 = lane & 15;
  const int quad = lane >> 4;

  // ---- load Q tile: [64][192] = nope(128) | pe(64) ----
#pragma unroll
  for (int it = 0; it < 4; ++it) {
    const int idx = it * 256 + tid;
    const int r = idx >> 4;
    const int c = (idx & 15) * 8;
    const size_t t = (size_t)(b * S_LEN + qb + r);
    *(f16x8*)(&Qs[r][c]) = *(const f16x8*)(q_nope + t * (NH * DN) + h * DN + c);
  }
#pragma unroll
  for (int it = 0; it < 2; ++it) {
    const int idx = it * 256 + tid;
    const int r = idx >> 3;
    const int c = (idx & 7) * 8;
    const size_t t = (size_t)(b * S_LEN + qb + r);
    *(f16x8*)(&Qs[r][128 + c]) = *(const f16x8*)(q_pe + t * (NH * DR) + h * DR + c);
  }

  const fx4 fz = {0.f, 0.f, 0.f, 0.f};
  fx4 o_acc[8];
#pragma unroll
  for (int n = 0; n < 8; ++n) o_acc[n] = fz;
  float m_st[4], l_st[4];
#pragma unroll
  for (int r = 0; r < 4; ++r) { m_st[r] = -__builtin_inff(); l_st[r] = 0.f; }

  const int nkt = qb / 32 + 2;                    // keys 0 .. qb+63
  const float scale = 0.07216878364870323f;       // 1/sqrt(192)

  for (int kt = 0; kt < nkt; ++kt) {
    const int kbase = kt * 32;
    // ---- stage K rows [32][192] and V^T [128][32] ----
#pragma unroll
    for (int it = 0; it < 2; ++it) {
      const int idx = it * 256 + tid;
      const int r = idx >> 4;
      const int c = (idx & 15) * 8;
      const size_t t = (size_t)(b * S_LEN + kbase + r);
      *(f16x8*)(&Ks[r][c]) = *(const f16x8*)(kv_up + t * (NH * 256) + h * 256 + c);
    }
    {
      const int r = tid >> 3;
      const int c = (tid & 7) * 8;
      const size_t t = (size_t)(b * S_LEN + kbase + r);
      *(f16x8*)(&Ks[r][128 + c]) = *(const f16x8*)(k_rope + t * DR + c);
    }
    {
      const int key = tid >> 3;
      const int dvc = (tid & 7) * 16;
      const size_t t = (size_t)(b * S_LEN + kbase + key);
      const _Float16* vp = kv_up + t * (NH * 256) + h * 256 + 128 + dvc;
      f16x8 v0 = *(const f16x8*)(vp);
      f16x8 v1 = *(const f16x8*)(vp + 8);
#pragma unroll
      for (int j = 0; j < 8; ++j) Vt[dvc + j][key] = v0[j];
#pragma unroll
      for (int j = 0; j < 8; ++j) Vt[dvc + 8 + j][key] = v1[j];
    }
    __syncthreads();  // (A) staging visible

    // ---- scores S = Q K^T for this wave's 16 rows x 32 keys ----
    fx4 sacc0 = fz, sacc1 = fz;
#pragma unroll
    for (int kk = 0; kk < 6; ++kk) {
      f16x8 aq = *(const f16x8*)(&Qs[wave * 16 + m16][kk * 32 + quad * 8]);
      f16x8 b0 = *(const f16x8*)(&Ks[m16][kk * 32 + quad * 8]);
      f16x8 b1 = *(const f16x8*)(&Ks[16 + m16][kk * 32 + quad * 8]);
      sacc0 = __builtin_amdgcn_mfma_f32_16x16x32_f16(aq, b0, sacc0, 0, 0, 0);
      sacc1 = __builtin_amdgcn_mfma_f32_16x16x32_f16(aq, b1, sacc1, 0, 0, 0);
    }

    // ---- online softmax (C/D layout: row = quad*4+r, col = lane&15) ----
    float alpha[4];
#pragma unroll
    for (int r = 0; r < 4; ++r) {
      const int qrow = qb + wave * 16 + quad * 4 + r;
      float s0 = (kbase + m16 <= qrow) ? sacc0[r] * scale : -__builtin_inff();
      float s1 = (kbase + 16 + m16 <= qrow) ? sacc1[r] * scale : -__builtin_inff();
      float mx = fmaxf(s0, s1);
#pragma unroll
      for (int d = 1; d < 16; d <<= 1) mx = fmaxf(mx, __shfl_xor(mx, d));
      const float mn = fmaxf(m_st[r], mx);
      const float al = __expf(m_st[r] - mn);
      const float p0 = __expf(s0 - mn);
      const float p1 = __expf(s1 - mn);
      float ls = p0 + p1;
#pragma unroll
      for (int d = 1; d < 16; d <<= 1) ls += __shfl_xor(ls, d);
      l_st[r] = l_st[r] * al + ls;
      m_st[r] = mn;
      alpha[r] = al;
      Ps[wave][quad * 4 + r][m16] = (_Float16)p0;
      Ps[wave][quad * 4 + r][16 + m16] = (_Float16)p1;
    }
#pragma unroll
    for (int n = 0; n < 8; ++n)
#pragma unroll
      for (int r = 0; r < 4; ++r) o_acc[n][r] *= alpha[r];
    __syncthreads();  // (B) Ps visible

    // ---- PV: P as A-operand, V^T frags as B-operand ----
    f16x8 pf = *(const f16x8*)(&Ps[wave][m16][quad * 8]);
#pragma unroll
    for (int n = 0; n < 8; ++n) {
      f16x8 vf = *(const f16x8*)(&Vt[n * 16 + m16][quad * 8]);
      o_acc[n] = __builtin_amdgcn_mfma_f32_16x16x32_f16(pf, vf, o_acc[n], 0, 0, 0);
    }
    __syncthreads();  // (C) reads done before next staging
  }

  float invl[4];
#pragma unroll
  for (int r = 0; r < 4; ++r) invl[r] = 1.0f / l_st[r];
#pragma unroll
  for (int n = 0; n < 8; ++n) {
#pragma unroll
    for (int r = 0; r < 4; ++r) {
      const int row = qb + wave * 16 + quad * 4 + r;
      const size_t t = (size_t)(b * S_LEN + row);
      out[t * (NH * DV) + h * DV + n * 16 + m16] = (_Float16)(o_acc[n][r] * invl[r]);
    }
  }
}

// ---------------- launch ----------------------------------------------------
extern "C" void kernel_launch(void* const* d_in, const int* in_sizes, int n_in,
                              void* d_out, int out_size, void* d_ws, size_t ws_size,
                              hipStream_t stream) {
  const float* x         = (const float*)d_in[0];
  const float* wq_down   = (const float*)d_in[1];
  const float* q_norm_w  = (const float*)d_in[2];
  const float* wq_up     = (const float*)d_in[3];
  const float* wq_rope   = (const float*)d_in[4];
  const float* wkv_down  = (const float*)d_in[5];
  const float* kv_norm_w = (const float*)d_in[6];
  const float* wkv_up    = (const float*)d_in[7];
  const float* wk_rope   = (const float*)d_in[8];
  const float* wo        = (const float*)d_in[9];
  float* out = (float*)d_out;

  char* ws = (char*)d_ws;
  size_t off = 0;
  auto alloc = [&](size_t bytes) {
    char* p = ws + off;
    off += (bytes + 255) & ~(size_t)255;
    return p;
  };
  // total ~134 MB of workspace
  _Float16* x_h     = (_Float16*)alloc((size_t)TOKENS * DIM * 2);
  _Float16* wqd_h   = (_Float16*)alloc((size_t)QR * DIM * 2);
  _Float16* wqu_h   = (_Float16*)alloc((size_t)NH * DN * QR * 2);
  _Float16* wqr_h   = (_Float16*)alloc((size_t)NH * DR * QR * 2);
  _Float16* wkvd_h  = (_Float16*)alloc((size_t)KVR * DIM * 2);
  _Float16* wkvu_h  = (_Float16*)alloc((size_t)NH * 256 * KVR * 2);
  _Float16* wkr_h   = (_Float16*)alloc((size_t)DR * DIM * 2);
  _Float16* wo_h    = (_Float16*)alloc((size_t)DIM * NH * DV * 2);
  _Float16* qc_h    = (_Float16*)alloc((size_t)TOKENS * QR * 2);
  _Float16* kvc_h   = (_Float16*)alloc((size_t)TOKENS * KVR * 2);
  _Float16* qnope_h = (_Float16*)alloc((size_t)TOKENS * NH * DN * 2);
  _Float16* qpe_h   = (_Float16*)alloc((size_t)TOKENS * NH * DR * 2);
  _Float16* kvup_h  = (_Float16*)alloc((size_t)TOKENS * NH * 256 * 2);
  _Float16* krope_h = (_Float16*)alloc((size_t)TOKENS * DR * 2);
  _Float16* attn_h  = (_Float16*)alloc((size_t)TOKENS * NH * DV * 2);

  auto cvt = [&](const float* src, _Float16* dst, size_t n) {
    int n4 = (int)(n / 4);
    cvt_f32_f16<<<dim3((n4 + 255) / 256), dim3(256), 0, stream>>>(src, dst, n4);
  };
  cvt(x, x_h, (size_t)TOKENS * DIM);
  cvt(wq_down, wqd_h, (size_t)QR * DIM);
  cvt(wq_up, wqu_h, (size_t)NH * DN * QR);
  cvt(wq_rope, wqr_h, (size_t)NH * DR * QR);
  cvt(wkv_down, wkvd_h, (size_t)KVR * DIM);
  cvt(wkv_up, wkvu_h, (size_t)NH * 256 * KVR);
  cvt(wk_rope, wkr_h, (size_t)DR * DIM);
  cvt(wo, wo_h, (size_t)DIM * NH * DV);

  auto gx = [](int n) { return (unsigned)((n + 127) / 128); };
  const unsigned gm = TOKENS / 128;

  // q path
  gemm_nt<_Float16><<<dim3(gx(QR), gm), 256, 0, stream>>>(x_h, wqd_h, qc_h, TOKENS, QR, DIM);
  rmsnorm_ip<QR><<<dim3(TOKENS), 256, 0, stream>>>(qc_h, q_norm_w);
  // kv path
  gemm_nt<_Float16><<<dim3(gx(KVR), gm), 256, 0, stream>>>(x_h, wkvd_h, kvc_h, TOKENS, KVR, DIM);
  rmsnorm_ip<KVR><<<dim3(TOKENS), 256, 0, stream>>>(kvc_h, kv_norm_w);
  // shared rope key
  gemm_nt<_Float16><<<dim3(gx(DR), gm), 256, 0, stream>>>(x_h, wkr_h, krope_h, TOKENS, DR, DIM);
  rope_k<<<dim3(TOKENS * 32 / 256), 256, 0, stream>>>(krope_h);
  // q up-projections
  gemm_nt<_Float16><<<dim3(gx(NH * DN), gm), 256, 0, stream>>>(qc_h, wqu_h, qnope_h, TOKENS, NH * DN, QR);
  gemm_nt<_Float16><<<dim3(gx(NH * DR), gm), 256, 0, stream>>>(qc_h, wqr_h, qpe_h, TOKENS, NH * DR, QR);
  rope_q<<<dim3(TOKENS * NH * 32 / 256), 256, 0, stream>>>(qpe_h);
  // kv up-projection
  gemm_nt<_Float16><<<dim3(gx(NH * 256), gm), 256, 0, stream>>>(kvc_h, wkvu_h, kvup_h, TOKENS, NH * 256, KVR);
  // attention
  mla_attention<<<dim3(S_LEN / 64, NH, BATCH), 256, 0, stream>>>(qnope_h, qpe_h, kvup_h, krope_h, attn_h);
  // output projection (fp32 out)
  gemm_nt<float><<<dim3(gx(DIM), gm), 256, 0, stream>>>(attn_h, wo_h, out, TOKENS, DIM, NH * DV);
}

// Round 2
// 704.641 us; speedup vs baseline: 1.3366x; 1.3366x over previous
//
#include <hip/hip_runtime.h>
#include <stdint.h>

typedef _Float16 f16x8 __attribute__((ext_vector_type(8)));
typedef _Float16 f16x4 __attribute__((ext_vector_type(4)));
typedef float fx4 __attribute__((ext_vector_type(4)));

static constexpr int S_LEN = 2048;
static constexpr int BATCH = 2;
static constexpr int TOKENS = BATCH * S_LEN;   // 4096
static constexpr int DIM = 2048;
static constexpr int NH = 16;
static constexpr int QR = 1536;
static constexpr int KVR = 512;
static constexpr int DN = 128;
static constexpr int DR = 64;
static constexpr int DV = 128;

// async global->LDS, 16B per lane; LDS dest = wave-uniform base + lane*16
__device__ __forceinline__ void async16(const _Float16* g, _Float16* lds_base_uniform) {
  __builtin_amdgcn_global_load_lds(
      (const __attribute__((address_space(1))) void*)g,
      (__attribute__((address_space(3))) void*)lds_base_uniform, 16, 0, 0);
}

// ---------------- f32 -> f16 conversion ----------------
__global__ void cvt_f32_f16(const float* __restrict__ in, _Float16* __restrict__ out, int n4) {
  int i = blockIdx.x * 256 + threadIdx.x;
  if (i >= n4) return;
  fx4 v = *(const fx4*)(in + (size_t)i * 4);
  f16x4 o;
  o[0] = (_Float16)v[0]; o[1] = (_Float16)v[1];
  o[2] = (_Float16)v[2]; o[3] = (_Float16)v[3];
  *(f16x4*)(out + (size_t)i * 4) = o;
}

// ---------------- NT GEMM, m97-style global_load_lds staging ---------------
// C[M,N] = A[M,K] * W[N,K]^T.  128x128 tile, BK=32, LDS unpadded [128][32].
// MODE 0: f16 C; MODE 1: f32 C; MODE 2: kv_up split -> knope [T,2048] + vT [2048,T]
template <int MODE>
__global__ __launch_bounds__(256) void gemm_nt(const _Float16* __restrict__ A,
                                               const _Float16* __restrict__ W,
                                               void* __restrict__ C0v,
                                               void* __restrict__ C1v,
                                               int M, int N, int K) {
  __shared__ __attribute__((aligned(16))) _Float16 As[128 * 32];
  __shared__ __attribute__((aligned(16))) _Float16 Ws[128 * 32];
  const int tid = threadIdx.x;
  const int lane = tid & 63;
  const int wave = tid >> 6;
  const int wr = (wave >> 1) * 64;
  const int wc = (wave & 1) * 64;
  const int m16 = lane & 15;
  const int quad = lane >> 4;
  const int m0 = blockIdx.y * 128;
  const int n0 = blockIdx.x * 128;

  const fx4 fz = {0.f, 0.f, 0.f, 0.f};
  fx4 acc[4][4];
#pragma unroll
  for (int i = 0; i < 4; ++i)
#pragma unroll
    for (int j = 0; j < 4; ++j) acc[i][j] = fz;

  for (int k0 = 0; k0 < K; k0 += 32) {
    // stage 2 x 8KB tiles: 512 chunks of 16B each; wave handles lane-linear runs
#pragma unroll
    for (int p = 0; p < 2; ++p) {
      const int cb = p * 256 + wave * 64;   // wave-uniform chunk base
      const int ch = cb + lane;
      const int r = ch >> 2;
      const int c8 = (ch & 3) * 8;
      // NOTE: rows n0+r may exceed N (only for the N=64 gemm); reads stay
      // inside the workspace allocation (finite poison), results discarded.
      async16(A + (size_t)(m0 + r) * K + k0 + c8, &As[cb * 8]);
      async16(W + (size_t)(n0 + r) * K + k0 + c8, &Ws[cb * 8]);
    }
    __syncthreads();
    f16x8 af[4], wf[4];
#pragma unroll
    for (int i = 0; i < 4; ++i)
      af[i] = *(const f16x8*)(&As[(wr + i * 16 + m16) * 32 + quad * 8]);
#pragma unroll
    for (int j = 0; j < 4; ++j)
      wf[j] = *(const f16x8*)(&Ws[(wc + j * 16 + m16) * 32 + quad * 8]);
#pragma unroll
    for (int i = 0; i < 4; ++i)
#pragma unroll
      for (int j = 0; j < 4; ++j)
        acc[i][j] = __builtin_amdgcn_mfma_f32_16x16x32_f16(af[i], wf[j], acc[i][j], 0, 0, 0);
    __syncthreads();
  }

  if (MODE == 2) {
    _Float16* KN = (_Float16*)C0v;
    _Float16* VT = (_Float16*)C1v;
#pragma unroll
    for (int j = 0; j < 4; ++j) {
      const int col = n0 + wc + j * 16 + m16;
      const int head = col >> 8;
      const int sub = col & 255;
      if (sub < 128) {
#pragma unroll
        for (int i = 0; i < 4; ++i)
#pragma unroll
          for (int r = 0; r < 4; ++r)
            KN[(size_t)(m0 + wr + i * 16 + quad * 4 + r) * 2048 + head * 128 + sub] =
                (_Float16)acc[i][j][r];
      } else {
        const int dv = sub - 128;
#pragma unroll
        for (int i = 0; i < 4; ++i) {
          f16x4 v;
#pragma unroll
          for (int r = 0; r < 4; ++r) v[r] = (_Float16)acc[i][j][r];
          *(f16x4*)(&VT[(size_t)(head * 128 + dv) * TOKENS + m0 + wr + i * 16 + quad * 4]) = v;
        }
      }
    }
  } else {
#pragma unroll
    for (int j = 0; j < 4; ++j) {
      const int col = n0 + wc + j * 16 + m16;
      if (col < N) {
#pragma unroll
        for (int i = 0; i < 4; ++i) {
#pragma unroll
          for (int r = 0; r < 4; ++r) {
            const size_t row = (size_t)(m0 + wr + i * 16 + quad * 4 + r);
            if (MODE == 0) ((_Float16*)C0v)[row * N + col] = (_Float16)acc[i][j][r];
            else ((float*)C0v)[row * N + col] = acc[i][j][r];
          }
        }
      }
    }
  }
}

// ---------------- in-place RMSNorm over f16 rows (fp32 math) ---------------
template <int NC>
__global__ __launch_bounds__(256) void rmsnorm_ip(_Float16* __restrict__ xx,
                                                  const float* __restrict__ w) {
  const int row = blockIdx.x;
  _Float16* p = xx + (size_t)row * NC;
  float ss = 0.f;
  for (int c = threadIdx.x; c < NC; c += 256) {
    const float v = (float)p[c];
    ss += v * v;
  }
#pragma unroll
  for (int d = 1; d < 64; d <<= 1) ss += __shfl_xor(ss, d);
  __shared__ float red[4];
  if ((threadIdx.x & 63) == 0) red[threadIdx.x >> 6] = ss;
  __syncthreads();
  const float rs = rsqrtf((red[0] + red[1] + red[2] + red[3]) * (1.0f / NC) + 1e-6f);
  for (int c = threadIdx.x; c < NC; c += 256)
    p[c] = (_Float16)((float)p[c] * rs * w[c]);
}

// ---------------- in-place RoPE (LLaMA interleaved pairs, d=64) ------------
__global__ void rope_q(_Float16* __restrict__ qpe) {  // [T, NH*64]
  const int idx = blockIdx.x * 256 + threadIdx.x;     // T*NH*32 threads
  const int t = idx >> 9;
  const int rem = idx & 511;
  const int hh = rem >> 5;
  const int i = rem & 31;
  const int s = t & (S_LEN - 1);
  const float fr = exp2f(-(float)i * 0.4152410118609203f);  // log2(1e4)/32
  const float ang = (float)s * fr;
  const float sn = sinf(ang), cs = cosf(ang);
  const size_t base = (size_t)t * (NH * DR) + hh * DR + 2 * i;
  const float x1 = (float)qpe[base];
  const float x2 = (float)qpe[base + 1];
  qpe[base] = (_Float16)(x1 * cs - x2 * sn);
  qpe[base + 1] = (_Float16)(x1 * sn + x2 * cs);
}

__global__ void rope_k(_Float16* __restrict__ kr) {  // [T, 64]
  const int idx = blockIdx.x * 256 + threadIdx.x;    // T*32 threads
  const int t = idx >> 5;
  const int i = idx & 31;
  const int s = t & (S_LEN - 1);
  const float fr = exp2f(-(float)i * 0.4152410118609203f);
  const float ang = (float)s * fr;
  const float sn = sinf(ang), cs = cosf(ang);
  const size_t base = (size_t)t * DR + 2 * i;
  const float x1 = (float)kr[base];
  const float x2 = (float)kr[base + 1];
  kr[base] = (_Float16)(x1 * cs - x2 * sn);
  kr[base + 1] = (_Float16)(x1 * sn + x2 * cs);
}

// ---------------- barrier-free causal flash attention ----------------------
// 1-D grid of 512 blocks; block = 4 waves; wave owns 32 q-rows (block 128).
// Q frags in registers; K and V^T frags read direct global->reg (16B each);
// only the P (C-layout -> A-layout) transpose uses wave-PRIVATE LDS: no
// __syncthreads anywhere (wave-internal lgkmcnt ordering is compiler-inserted).
__global__ __launch_bounds__(256, 2) void mla_attn(
    const _Float16* __restrict__ qn,   // [T, NH*128]
    const _Float16* __restrict__ qp,   // [T, NH*64]  roped
    const _Float16* __restrict__ kn,   // [T, NH*128]
    const _Float16* __restrict__ kr,   // [T, 64]     roped
    const _Float16* __restrict__ vT,   // [NH*128, T]
    _Float16* __restrict__ out)        // [T, NH*128]
{
  __shared__ __attribute__((aligned(16))) _Float16 Ps[4][32][72];

  const int bid = blockIdx.x;
  const int b = bid >> 8;
  const int u = bid & 255;
  const int h = u >> 4;
  const int xq = u & 15;
  // complementary lengths for blocks bid and bid+256 (likely same CU)
  const int q16 = b ? (15 - xq) : xq;
  const int qb = q16 * 128;
  const int tok0 = b * S_LEN;

  const int tid = threadIdx.x;
  const int lane = tid & 63;
  const int wave = tid >> 6;
  const int m16 = lane & 15;
  const int quad = lane >> 4;

  // ---- Q fragments (A-layout), loaded once ----
  f16x8 qf[2][6];
#pragma unroll
  for (int rg = 0; rg < 2; ++rg) {
    const size_t t = (size_t)(tok0 + qb + wave * 32 + rg * 16 + m16);
#pragma unroll
    for (int kk = 0; kk < 4; ++kk)
      qf[rg][kk] = *(const f16x8*)(qn + t * 2048 + h * 128 + kk * 32 + quad * 8);
#pragma unroll
    for (int kk = 0; kk < 2; ++kk)
      qf[rg][4 + kk] = *(const f16x8*)(qp + t * 1024 + h * 64 + kk * 32 + quad * 8);
  }

  const fx4 fz = {0.f, 0.f, 0.f, 0.f};
  fx4 oacc[2][8];
#pragma unroll
  for (int rg = 0; rg < 2; ++rg)
#pragma unroll
    for (int n = 0; n < 8; ++n) oacc[rg][n] = fz;
  float mst[2][4], lst[2][4];
#pragma unroll
  for (int rg = 0; rg < 2; ++rg)
#pragma unroll
    for (int r = 0; r < 4; ++r) { mst[rg][r] = -3.0e38f; lst[rg][r] = 0.f; }

  const float scale = 0.07216878364870323f;  // 1/sqrt(192)
  const int nkt = qb / 64 + 2;               // keys 0 .. qb+127

  for (int kt = 0; kt < nkt; ++kt) {
    const int kbase = kt * 64;
    const bool masked = (kt >= nkt - 2);

    // ---- S = Q K^T (two 16-row groups x 64 keys) ----
    fx4 sc[2][4];
#pragma unroll
    for (int rg = 0; rg < 2; ++rg)
#pragma unroll
      for (int n = 0; n < 4; ++n) sc[rg][n] = fz;
#pragma unroll 2
    for (int n = 0; n < 4; ++n) {
      const size_t t = (size_t)(tok0 + kbase + n * 16 + m16);
      f16x8 kf[6];
#pragma unroll
      for (int kk = 0; kk < 4; ++kk)
        kf[kk] = *(const f16x8*)(kn + t * 2048 + h * 128 + kk * 32 + quad * 8);
#pragma unroll
      for (int kk = 0; kk < 2; ++kk)
        kf[4 + kk] = *(const f16x8*)(kr + t * 64 + kk * 32 + quad * 8);
#pragma unroll
      for (int kk = 0; kk < 6; ++kk) {
        sc[0][n] = __builtin_amdgcn_mfma_f32_16x16x32_f16(qf[0][kk], kf[kk], sc[0][n], 0, 0, 0);
        sc[1][n] = __builtin_amdgcn_mfma_f32_16x16x32_f16(qf[1][kk], kf[kk], sc[1][n], 0, 0, 0);
      }
    }

    // ---- online softmax in C/D layout (row = quad*4+r, col = n*16+m16) ----
#pragma unroll
    for (int rg = 0; rg < 2; ++rg) {
      float alpha[4];
#pragma unroll
      for (int r = 0; r < 4; ++r) {
        float v0 = sc[rg][0][r] * scale;
        float v1 = sc[rg][1][r] * scale;
        float v2 = sc[rg][2][r] * scale;
        float v3 = sc[rg][3][r] * scale;
        if (masked) {
          const int qrow = qb + wave * 32 + rg * 16 + quad * 4 + r;
          if (kbase + m16 > qrow)      v0 = -3.0e38f;
          if (kbase + 16 + m16 > qrow) v1 = -3.0e38f;
          if (kbase + 32 + m16 > qrow) v2 = -3.0e38f;
          if (kbase + 48 + m16 > qrow) v3 = -3.0e38f;
        }
        float mx = fmaxf(fmaxf(v0, v1), fmaxf(v2, v3));
#pragma unroll
        for (int d = 1; d < 16; d <<= 1) mx = fmaxf(mx, __shfl_xor(mx, d));
        const float mn = fmaxf(mst[rg][r], mx);
        const float al = __expf(mst[rg][r] - mn);
        const float p0 = __expf(v0 - mn);
        const float p1 = __expf(v1 - mn);
        const float p2 = __expf(v2 - mn);
        const float p3 = __expf(v3 - mn);
        float ls = p0 + p1 + p2 + p3;
#pragma unroll
        for (int d = 1; d < 16; d <<= 1) ls += __shfl_xor(ls, d);
        mst[rg][r] = mn;
        lst[rg][r] = lst[rg][r] * al + ls;
        alpha[r] = al;
        _Float16* pr = &Ps[wave][rg * 16 + quad * 4 + r][0];
        pr[m16] = (_Float16)p0;
        pr[16 + m16] = (_Float16)p1;
        pr[32 + m16] = (_Float16)p2;
        pr[48 + m16] = (_Float16)p3;
      }
#pragma unroll
      for (int n8 = 0; n8 < 8; ++n8)
#pragma unroll
        for (int r = 0; r < 4; ++r) oacc[rg][n8][r] *= alpha[r];
    }

    // ---- O += P V  (P from wave-private LDS in A-layout; V^T direct) ----
    f16x8 pf0[2], pf1[2];
#pragma unroll
    for (int kf = 0; kf < 2; ++kf) {
      pf0[kf] = *(const f16x8*)(&Ps[wave][m16][kf * 32 + quad * 8]);
      pf1[kf] = *(const f16x8*)(&Ps[wave][16 + m16][kf * 32 + quad * 8]);
    }
#pragma unroll
    for (int n8 = 0; n8 < 8; ++n8) {
      const _Float16* vp = vT + (size_t)(h * 128 + n8 * 16 + m16) * TOKENS + tok0 + kbase;
#pragma unroll
      for (int kf = 0; kf < 2; ++kf) {
        f16x8 vf = *(const f16x8*)(vp + kf * 32 + quad * 8);
        oacc[0][n8] = __builtin_amdgcn_mfma_f32_16x16x32_f16(pf0[kf], vf, oacc[0][n8], 0, 0, 0);
        oacc[1][n8] = __builtin_amdgcn_mfma_f32_16x16x32_f16(pf1[kf], vf, oacc[1][n8], 0, 0, 0);
      }
    }
  }

  // ---- epilogue ----
#pragma unroll
  for (int rg = 0; rg < 2; ++rg) {
    float inv[4];
#pragma unroll
    for (int r = 0; r < 4; ++r) inv[r] = 1.0f / lst[rg][r];
#pragma unroll
    for (int n8 = 0; n8 < 8; ++n8) {
#pragma unroll
      for (int r = 0; r < 4; ++r) {
        const size_t t = (size_t)(tok0 + qb + wave * 32 + rg * 16 + quad * 4 + r);
        out[t * 2048 + h * 128 + n8 * 16 + m16] = (_Float16)(oacc[rg][n8][r] * inv[r]);
      }
    }
  }
}

// ---------------- launch ----------------------------------------------------
extern "C" void kernel_launch(void* const* d_in, const int* in_sizes, int n_in,
                              void* d_out, int out_size, void* d_ws, size_t ws_size,
                              hipStream_t stream) {
  const float* x         = (const float*)d_in[0];
  const float* wq_down   = (const float*)d_in[1];
  const float* q_norm_w  = (const float*)d_in[2];
  const float* wq_up     = (const float*)d_in[3];
  const float* wq_rope   = (const float*)d_in[4];
  const float* wkv_down  = (const float*)d_in[5];
  const float* kv_norm_w = (const float*)d_in[6];
  const float* wkv_up    = (const float*)d_in[7];
  const float* wk_rope   = (const float*)d_in[8];
  const float* wo        = (const float*)d_in[9];
  float* out = (float*)d_out;

  char* ws = (char*)d_ws;
  size_t off = 0;
  auto alloc = [&](size_t bytes) {
    char* p = ws + off;
    off += (bytes + 255) & ~(size_t)255;
    return p;
  };
  _Float16* x_h     = (_Float16*)alloc((size_t)TOKENS * DIM * 2);
  _Float16* wqd_h   = (_Float16*)alloc((size_t)QR * DIM * 2);
  _Float16* wqu_h   = (_Float16*)alloc((size_t)NH * DN * QR * 2);
  _Float16* wqr_h   = (_Float16*)alloc((size_t)NH * DR * QR * 2);
  _Float16* wkvd_h  = (_Float16*)alloc((size_t)KVR * DIM * 2);
  _Float16* wkvu_h  = (_Float16*)alloc((size_t)NH * 256 * KVR * 2);
  _Float16* wkr_h   = (_Float16*)alloc((size_t)DR * DIM * 2);   // OOB-read pad follows
  _Float16* wo_h    = (_Float16*)alloc((size_t)DIM * NH * DV * 2);
  _Float16* qc_h    = (_Float16*)alloc((size_t)TOKENS * QR * 2);
  _Float16* kvc_h   = (_Float16*)alloc((size_t)TOKENS * KVR * 2);
  _Float16* qnope_h = (_Float16*)alloc((size_t)TOKENS * NH * DN * 2);
  _Float16* qpe_h   = (_Float16*)alloc((size_t)TOKENS * NH * DR * 2);
  _Float16* knope_h = (_Float16*)alloc((size_t)TOKENS * NH * DN * 2);
  _Float16* vT_h    = (_Float16*)alloc((size_t)NH * DV * TOKENS * 2);
  _Float16* krope_h = (_Float16*)alloc((size_t)TOKENS * DR * 2);
  _Float16* attn_h  = (_Float16*)alloc((size_t)TOKENS * NH * DV * 2);

  auto cvt = [&](const float* src, _Float16* dst, size_t n) {
    int n4 = (int)(n / 4);
    cvt_f32_f16<<<dim3((n4 + 255) / 256), dim3(256), 0, stream>>>(src, dst, n4);
  };
  cvt(x, x_h, (size_t)TOKENS * DIM);
  cvt(wq_down, wqd_h, (size_t)QR * DIM);
  cvt(wq_up, wqu_h, (size_t)NH * DN * QR);
  cvt(wq_rope, wqr_h, (size_t)NH * DR * QR);
  cvt(wkv_down, wkvd_h, (size_t)KVR * DIM);
  cvt(wkv_up, wkvu_h, (size_t)NH * 256 * KVR);
  cvt(wk_rope, wkr_h, (size_t)DR * DIM);
  cvt(wo, wo_h, (size_t)DIM * NH * DV);

  auto gx = [](int n) { return (unsigned)((n + 127) / 128); };
  const unsigned gm = TOKENS / 128;

  // q path
  gemm_nt<0><<<dim3(gx(QR), gm), 256, 0, stream>>>(x_h, wqd_h, qc_h, nullptr, TOKENS, QR, DIM);
  rmsnorm_ip<QR><<<dim3(TOKENS), 256, 0, stream>>>(qc_h, q_norm_w);
  // kv path
  gemm_nt<0><<<dim3(gx(KVR), gm), 256, 0, stream>>>(x_h, wkvd_h, kvc_h, nullptr, TOKENS, KVR, DIM);
  rmsnorm_ip<KVR><<<dim3(TOKENS), 256, 0, stream>>>(kvc_h, kv_norm_w);
  // shared rope key
  gemm_nt<0><<<dim3(gx(DR), gm), 256, 0, stream>>>(x_h, wkr_h, krope_h, nullptr, TOKENS, DR, DIM);
  rope_k<<<dim3(TOKENS * 32 / 256), 256, 0, stream>>>(krope_h);
  // q up-projections
  gemm_nt<0><<<dim3(gx(NH * DN), gm), 256, 0, stream>>>(qc_h, wqu_h, qnope_h, nullptr, TOKENS, NH * DN, QR);
  gemm_nt<0><<<dim3(gx(NH * DR), gm), 256, 0, stream>>>(qc_h, wqr_h, qpe_h, nullptr, TOKENS, NH * DR, QR);
  rope_q<<<dim3(TOKENS * NH * 32 / 256), 256, 0, stream>>>(qpe_h);
  // kv up-projection, split epilogue: k_nope natural + V transposed
  gemm_nt<2><<<dim3(gx(NH * 256), gm), 256, 0, stream>>>(kvc_h, wkvu_h, knope_h, vT_h, TOKENS, NH * 256, KVR);
  // attention (barrier-free)
  mla_attn<<<dim3(512), 256, 0, stream>>>(qnope_h, qpe_h, knope_h, krope_h, vT_h, attn_h);
  // output projection (fp32 out)
  gemm_nt<1><<<dim3(gx(DIM), gm), 256, 0, stream>>>(attn_h, wo_h, out, nullptr, TOKENS, DIM, NH * DV);
}

// Round 3
// 595.595 us; speedup vs baseline: 1.5813x; 1.1831x over previous
//
#include <hip/hip_runtime.h>
#include <stdint.h>

typedef _Float16 f16x8 __attribute__((ext_vector_type(8)));
typedef _Float16 f16x4 __attribute__((ext_vector_type(4)));
typedef float fx4 __attribute__((ext_vector_type(4)));

static constexpr int S_LEN = 2048;
static constexpr int BATCH = 2;
static constexpr int TOKENS = BATCH * S_LEN;   // 4096
static constexpr int DIM = 2048;
static constexpr int NH = 16;
static constexpr int QR = 1536;
static constexpr int KVR = 512;
static constexpr int DN = 128;
static constexpr int DR = 64;
static constexpr int DV = 128;

// async global->LDS, 16B per lane; LDS dest = wave-uniform base, HW adds lane*16
__device__ __forceinline__ void async16(const _Float16* g, _Float16* lds_base_uniform) {
  __builtin_amdgcn_global_load_lds(
      (const __attribute__((address_space(1))) void*)g,
      (__attribute__((address_space(3))) void*)lds_base_uniform, 16, 0, 0);
}

// ---------------- fused f32 -> f16 conversion (all tensors, one dispatch) ---
struct CvtSegs {
  const float* src[8];
  _Float16* dst[8];
  int n4[8];
  int cum[9];
};
__global__ __launch_bounds__(256) void cvt_all(CvtSegs s) {
  const int b = blockIdx.x;
  int seg = 0;
#pragma unroll
  for (int k = 0; k < 7; ++k) seg += (b >= s.cum[seg + 1]) ? 1 : 0;
  const int i = (b - s.cum[seg]) * 256 + threadIdx.x;
  if (i >= s.n4[seg]) return;
  fx4 v = *(const fx4*)(s.src[seg] + (size_t)i * 4);
  f16x4 o;
  o[0] = (_Float16)v[0]; o[1] = (_Float16)v[1];
  o[2] = (_Float16)v[2]; o[3] = (_Float16)v[3];
  *(f16x4*)(s.dst[seg] + (size_t)i * 4) = o;
}

// ---------------- NT GEMM, double-buffered LDS, ONE barrier per K-iter -----
// C[M,N] = A[M,K] * W[N,K]^T.  128x128 tile, BK=32.
// MODE 0: f16 C0.  MODE 1: f32 C0.  MODE 2: split knope[T,2048] + vT[2048,T].
// MODE 3: split qnope[.,2048] + qpe[.,1024].  MODE 4: split kvc[.,512] + krope[.,64].
template <int MODE>
__global__ __launch_bounds__(256) void gemm_nt(const _Float16* __restrict__ A,
                                               const _Float16* __restrict__ W,
                                               void* __restrict__ C0v,
                                               void* __restrict__ C1v,
                                               int M, int N, int K) {
  __shared__ __attribute__((aligned(16))) _Float16 As[2][128 * 32];
  __shared__ __attribute__((aligned(16))) _Float16 Ws[2][128 * 32];
  const int tid = threadIdx.x;
  const int lane = tid & 63;
  const int wave = tid >> 6;
  const int wr = (wave >> 1) * 64;
  const int wc = (wave & 1) * 64;
  const int m16 = lane & 15;
  const int quad = lane >> 4;
  const int m0 = blockIdx.y * 128;
  const int n0 = blockIdx.x * 128;

  auto stage = [&](int buf, int k0) {
#pragma unroll
    for (int p = 0; p < 2; ++p) {
      const int cb = p * 256 + wave * 64;   // wave-uniform chunk base
      const int ch = cb + lane;
      const int r = ch >> 2;
      const int c8 = (ch & 3) * 8;
      // W rows n0+r may exceed N (N=576 gemm); reads stay inside workspace.
      async16(A + (size_t)(m0 + r) * K + k0 + c8, &As[buf][cb * 8]);
      async16(W + (size_t)(n0 + r) * K + k0 + c8, &Ws[buf][cb * 8]);
    }
  };

  const fx4 fz = {0.f, 0.f, 0.f, 0.f};
  fx4 acc[4][4];
#pragma unroll
  for (int i = 0; i < 4; ++i)
#pragma unroll
    for (int j = 0; j < 4; ++j) acc[i][j] = fz;

  const int nkt = K >> 5;
  stage(0, 0);
  for (int kt = 0; kt < nkt; ++kt) {
    __syncthreads();                       // drains buf[kt&1] loads (in flight all last iter)
    if (kt + 1 < nkt) stage((kt + 1) & 1, (kt + 1) * 32);   // overlaps compute below
    const _Float16* as = As[kt & 1];
    const _Float16* ws = Ws[kt & 1];
    f16x8 af[4], wf[4];
#pragma unroll
    for (int i = 0; i < 4; ++i)
      af[i] = *(const f16x8*)(&as[(wr + i * 16 + m16) * 32 + quad * 8]);
#pragma unroll
    for (int j = 0; j < 4; ++j)
      wf[j] = *(const f16x8*)(&ws[(wc + j * 16 + m16) * 32 + quad * 8]);
#pragma unroll
    for (int i = 0; i < 4; ++i)
#pragma unroll
      for (int j = 0; j < 4; ++j)
        acc[i][j] = __builtin_amdgcn_mfma_f32_16x16x32_f16(af[i], wf[j], acc[i][j], 0, 0, 0);
  }

#pragma unroll
  for (int j = 0; j < 4; ++j) {
    const int col = n0 + wc + j * 16 + m16;
    if (MODE == 2) {
      _Float16* KN = (_Float16*)C0v;
      _Float16* VT = (_Float16*)C1v;
      const int head = col >> 8;
      const int sub = col & 255;
      if (sub < 128) {
#pragma unroll
        for (int i = 0; i < 4; ++i)
#pragma unroll
          for (int r = 0; r < 4; ++r)
            KN[(size_t)(m0 + wr + i * 16 + quad * 4 + r) * 2048 + head * 128 + sub] =
                (_Float16)acc[i][j][r];
      } else {
        const int dv = sub - 128;
#pragma unroll
        for (int i = 0; i < 4; ++i) {
          f16x4 v;
#pragma unroll
          for (int r = 0; r < 4; ++r) v[r] = (_Float16)acc[i][j][r];
          *(f16x4*)(&VT[(size_t)(head * 128 + dv) * TOKENS + m0 + wr + i * 16 + quad * 4]) = v;
        }
      }
    } else if (MODE == 3) {
#pragma unroll
      for (int i = 0; i < 4; ++i)
#pragma unroll
        for (int r = 0; r < 4; ++r) {
          const size_t row = (size_t)(m0 + wr + i * 16 + quad * 4 + r);
          if (col < 2048) ((_Float16*)C0v)[row * 2048 + col] = (_Float16)acc[i][j][r];
          else ((_Float16*)C1v)[row * 1024 + col - 2048] = (_Float16)acc[i][j][r];
        }
    } else if (MODE == 4) {
      if (col < 576) {
#pragma unroll
        for (int i = 0; i < 4; ++i)
#pragma unroll
          for (int r = 0; r < 4; ++r) {
            const size_t row = (size_t)(m0 + wr + i * 16 + quad * 4 + r);
            if (col < 512) ((_Float16*)C0v)[row * 512 + col] = (_Float16)acc[i][j][r];
            else ((_Float16*)C1v)[row * 64 + col - 512] = (_Float16)acc[i][j][r];
          }
      }
    } else {
      if (col < N) {
#pragma unroll
        for (int i = 0; i < 4; ++i)
#pragma unroll
          for (int r = 0; r < 4; ++r) {
            const size_t row = (size_t)(m0 + wr + i * 16 + quad * 4 + r);
            if (MODE == 0) ((_Float16*)C0v)[row * N + col] = (_Float16)acc[i][j][r];
            else ((float*)C0v)[row * N + col] = acc[i][j][r];
          }
      }
    }
  }
}

// ---------------- in-place RMSNorm over f16 rows (fp32 math) ---------------
template <int NC>
__global__ __launch_bounds__(256) void rmsnorm_ip(_Float16* __restrict__ xx,
                                                  const float* __restrict__ w) {
  const int row = blockIdx.x;
  _Float16* p = xx + (size_t)row * NC;
  float ss = 0.f;
  for (int c = threadIdx.x; c < NC; c += 256) {
    const float v = (float)p[c];
    ss += v * v;
  }
#pragma unroll
  for (int d = 1; d < 64; d <<= 1) ss += __shfl_xor(ss, d);
  __shared__ float red[4];
  if ((threadIdx.x & 63) == 0) red[threadIdx.x >> 6] = ss;
  __syncthreads();
  const float rs = rsqrtf((red[0] + red[1] + red[2] + red[3]) * (1.0f / NC) + 1e-6f);
  for (int c = threadIdx.x; c < NC; c += 256)
    p[c] = (_Float16)((float)p[c] * rs * w[c]);
}

// ---------------- in-place RoPE (LLaMA interleaved pairs, d=64) ------------
__global__ void rope_q(_Float16* __restrict__ qpe) {  // [T, NH*64]
  const int idx = blockIdx.x * 256 + threadIdx.x;     // T*NH*32 threads
  const int t = idx >> 9;
  const int rem = idx & 511;
  const int hh = rem >> 5;
  const int i = rem & 31;
  const int s = t & (S_LEN - 1);
  const float fr = exp2f(-(float)i * 0.4152410118609203f);  // log2(1e4)/32
  const float ang = (float)s * fr;
  const float sn = sinf(ang), cs = cosf(ang);
  const size_t base = (size_t)t * (NH * DR) + hh * DR + 2 * i;
  const float x1 = (float)qpe[base];
  const float x2 = (float)qpe[base + 1];
  qpe[base] = (_Float16)(x1 * cs - x2 * sn);
  qpe[base + 1] = (_Float16)(x1 * sn + x2 * cs);
}

__global__ void rope_k(_Float16* __restrict__ kr) {  // [T, 64]
  const int idx = blockIdx.x * 256 + threadIdx.x;    // T*32 threads
  const int t = idx >> 5;
  const int i = idx & 31;
  const int s = t & (S_LEN - 1);
  const float fr = exp2f(-(float)i * 0.4152410118609203f);
  const float ang = (float)s * fr;
  const float sn = sinf(ang), cs = cosf(ang);
  const size_t base = (size_t)t * DR + 2 * i;
  const float x1 = (float)kr[base];
  const float x2 = (float)kr[base + 1];
  kr[base] = (_Float16)(x1 * cs - x2 * sn);
  kr[base + 1] = (_Float16)(x1 * sn + x2 * cs);
}

// ---------------- causal flash attention v3 --------------------------------
// Block = 4 waves x 32 q-rows = 128 q-rows, one (batch, head, q-tile).
// K-tiles (32 keys x 192 dims) staged in LDS chunk-major via global_load_lds,
// double-buffered, ONE __syncthreads per tile:
//   sync(drains kt loads) -> V reg-loads -> issue prefetch kt+1 -> compute kt.
// V read direct global->reg from vT. P transpose via wave-private LDS.
__global__ __launch_bounds__(256, 2) void mla_attn(
    const _Float16* __restrict__ qn,   // [T, NH*128]
    const _Float16* __restrict__ qp,   // [T, NH*64]  roped
    const _Float16* __restrict__ kn,   // [T, NH*128]
    const _Float16* __restrict__ kr,   // [T, 64]     roped
    const _Float16* __restrict__ vT,   // [NH*128, T]
    _Float16* __restrict__ out)        // [T, NH*128]
{
  // chunk-major K: chunk c = ch*32+key (ch 0..23 = 16B chunk of 192-dim, key 0..31)
  __shared__ __attribute__((aligned(16))) _Float16 Ks[2][768 * 8];
  __shared__ __attribute__((aligned(16))) _Float16 Ps[4][32][40];

  const int bid = blockIdx.x;
  const int b = bid >> 8;
  const int u = bid & 255;
  const int h = u >> 4;
  const int xq = u & 15;
  const int q16 = b ? (15 - xq) : xq;   // complementary pairing across batches
  const int qb = q16 * 128;
  const int tok0 = b * S_LEN;

  const int tid = threadIdx.x;
  const int lane = tid & 63;
  const int wave = tid >> 6;
  const int m16 = lane & 15;
  const int quad = lane >> 4;
  const int R0 = qb + wave * 32;        // this wave's first q-row

  auto stageK = [&](int buf, int kbase) {
#pragma unroll
    for (int j = 0; j < 3; ++j) {
      const int i = wave * 3 + j;             // instr 0..11
      const int ch = i * 2 + (lane >> 5);     // wave-uniform side of 16
      const int key = lane & 31;
      const _Float16* g = (ch < 16)
          ? kn + (size_t)(tok0 + kbase + key) * 2048 + h * 128 + ch * 8
          : kr + (size_t)(tok0 + kbase + key) * 64 + (ch - 16) * 8;
      async16(g, &Ks[buf][i * 512]);
    }
  };

  // ---- Q fragments (A-layout), loaded once ----
  f16x8 qf[2][6];
#pragma unroll
  for (int rg = 0; rg < 2; ++rg) {
    const size_t t = (size_t)(tok0 + qb + wave * 32 + rg * 16 + m16);
#pragma unroll
    for (int kk = 0; kk < 4; ++kk)
      qf[rg][kk] = *(const f16x8*)(qn + t * 2048 + h * 128 + kk * 32 + quad * 8);
#pragma unroll
    for (int kk = 0; kk < 2; ++kk)
      qf[rg][4 + kk] = *(const f16x8*)(qp + t * 1024 + h * 64 + kk * 32 + quad * 8);
  }

  const fx4 fz = {0.f, 0.f, 0.f, 0.f};
  fx4 oacc[2][8];
#pragma unroll
  for (int rg = 0; rg < 2; ++rg)
#pragma unroll
    for (int n = 0; n < 8; ++n) oacc[rg][n] = fz;
  float mst[2][4], lst[2][4];
#pragma unroll
  for (int rg = 0; rg < 2; ++rg)
#pragma unroll
    for (int r = 0; r < 4; ++r) { mst[rg][r] = -3.0e38f; lst[rg][r] = 0.f; }

  const float scale = 0.07216878364870323f;  // 1/sqrt(192)
  const int nkt = qb / 32 + 4;               // key tiles: 0 .. qb+127

  stageK(0, 0);
  for (int kt = 0; kt < nkt; ++kt) {
    const int kbase = kt * 32;
    __syncthreads();                          // buf[kt&1] ready (in flight last iter)
    const bool live = (kbase <= R0 + 31);

    // V loads BEFORE prefetch-issue: consuming them waits vmcnt(12), not the prefetch
    f16x8 vf[8];
    if (live) {
#pragma unroll
      for (int n8 = 0; n8 < 8; ++n8)
        vf[n8] = *(const f16x8*)(vT + (size_t)(h * 128 + n8 * 16 + m16) * TOKENS +
                                 tok0 + kbase + quad * 8);
    }
    if (kt + 1 < nkt) stageK((kt + 1) & 1, kbase + 32);

    if (!live) continue;                      // fully-masked tile for this wave
    const _Float16* ks = Ks[kt & 1];

    // ---- S = Q K^T : 2 rg x 2 key-groups x 6 kk ----
    fx4 sc[2][2];
#pragma unroll
    for (int rg = 0; rg < 2; ++rg)
#pragma unroll
      for (int n = 0; n < 2; ++n) sc[rg][n] = fz;
#pragma unroll
    for (int kk = 0; kk < 6; ++kk) {
#pragma unroll
      for (int n = 0; n < 2; ++n) {
        f16x8 kf = *(const f16x8*)(&ks[(kk * 128 + quad * 32 + n * 16 + m16) * 8]);
        sc[0][n] = __builtin_amdgcn_mfma_f32_16x16x32_f16(qf[0][kk], kf, sc[0][n], 0, 0, 0);
        sc[1][n] = __builtin_amdgcn_mfma_f32_16x16x32_f16(qf[1][kk], kf, sc[1][n], 0, 0, 0);
      }
    }

    // ---- online softmax (C/D layout: row = quad*4+r, col = n*16+m16) ----
    const bool needmask = (kbase + 31 > R0);
#pragma unroll
    for (int rg = 0; rg < 2; ++rg) {
      float alpha[4];
#pragma unroll
      for (int r = 0; r < 4; ++r) {
        float v0 = sc[rg][0][r] * scale;
        float v1 = sc[rg][1][r] * scale;
        if (needmask) {
          const int qrow = R0 + rg * 16 + quad * 4 + r;
          if (kbase + m16 > qrow)      v0 = -3.0e38f;
          if (kbase + 16 + m16 > qrow) v1 = -3.0e38f;
        }
        float mx = fmaxf(v0, v1);
#pragma unroll
        for (int d = 1; d < 16; d <<= 1) mx = fmaxf(mx, __shfl_xor(mx, d));
        const float mn = fmaxf(mst[rg][r], mx);
        const float al = __expf(mst[rg][r] - mn);
        const float p0 = __expf(v0 - mn);
        const float p1 = __expf(v1 - mn);
        float ls = p0 + p1;
#pragma unroll
        for (int d = 1; d < 16; d <<= 1) ls += __shfl_xor(ls, d);
        mst[rg][r] = mn;
        lst[rg][r] = lst[rg][r] * al + ls;
        alpha[r] = al;
        _Float16* pr = &Ps[wave][rg * 16 + quad * 4 + r][0];
        pr[m16] = (_Float16)p0;
        pr[16 + m16] = (_Float16)p1;
      }
#pragma unroll
      for (int n8 = 0; n8 < 8; ++n8)
#pragma unroll
        for (int r = 0; r < 4; ++r) oacc[rg][n8][r] *= alpha[r];
    }

    // ---- O += P V  (P via wave-private LDS -> A-layout; V from regs) ----
    f16x8 pf0 = *(const f16x8*)(&Ps[wave][m16][quad * 8]);
    f16x8 pf1 = *(const f16x8*)(&Ps[wave][16 + m16][quad * 8]);
#pragma unroll
    for (int n8 = 0; n8 < 8; ++n8) {
      oacc[0][n8] = __builtin_amdgcn_mfma_f32_16x16x32_f16(pf0, vf[n8], oacc[0][n8], 0, 0, 0);
      oacc[1][n8] = __builtin_amdgcn_mfma_f32_16x16x32_f16(pf1, vf[n8], oacc[1][n8], 0, 0, 0);
    }
  }

  // ---- epilogue ----
#pragma unroll
  for (int rg = 0; rg < 2; ++rg) {
    float inv[4];
#pragma unroll
    for (int r = 0; r < 4; ++r) inv[r] = 1.0f / lst[rg][r];
#pragma unroll
    for (int n8 = 0; n8 < 8; ++n8) {
#pragma unroll
      for (int r = 0; r < 4; ++r) {
        const size_t t = (size_t)(tok0 + qb + wave * 32 + rg * 16 + quad * 4 + r);
        out[t * 2048 + h * 128 + n8 * 16 + m16] = (_Float16)(oacc[rg][n8][r] * inv[r]);
      }
    }
  }
}

// ---------------- launch ----------------------------------------------------
extern "C" void kernel_launch(void* const* d_in, const int* in_sizes, int n_in,
                              void* d_out, int out_size, void* d_ws, size_t ws_size,
                              hipStream_t stream) {
  const float* x         = (const float*)d_in[0];
  const float* wq_down   = (const float*)d_in[1];
  const float* q_norm_w  = (const float*)d_in[2];
  const float* wq_up     = (const float*)d_in[3];
  const float* wq_rope   = (const float*)d_in[4];
  const float* wkv_down  = (const float*)d_in[5];
  const float* kv_norm_w = (const float*)d_in[6];
  const float* wkv_up    = (const float*)d_in[7];
  const float* wk_rope   = (const float*)d_in[8];
  const float* wo        = (const float*)d_in[9];
  float* out = (float*)d_out;

  char* ws = (char*)d_ws;
  size_t off = 0;
  auto alloc = [&](size_t bytes) {
    char* p = ws + off;
    off += (bytes + 255) & ~(size_t)255;
    return p;
  };
  _Float16* x_h     = (_Float16*)alloc((size_t)TOKENS * DIM * 2);
  _Float16* wqd_h   = (_Float16*)alloc((size_t)QR * DIM * 2);
  _Float16* wquqr_h = (_Float16*)alloc((size_t)3072 * QR * 2);       // wq_up | wq_rope
  _Float16* wkvdr_h = (_Float16*)alloc((size_t)576 * DIM * 2);       // wkv_down | wk_rope
  _Float16* wkvu_h  = (_Float16*)alloc((size_t)NH * 256 * KVR * 2);
  _Float16* wo_h    = (_Float16*)alloc((size_t)DIM * NH * DV * 2);
  _Float16* qc_h    = (_Float16*)alloc((size_t)TOKENS * QR * 2);
  _Float16* kvc_h   = (_Float16*)alloc((size_t)TOKENS * KVR * 2);
  _Float16* qnope_h = (_Float16*)alloc((size_t)TOKENS * 2048 * 2);
  _Float16* qpe_h   = (_Float16*)alloc((size_t)TOKENS * 1024 * 2);
  _Float16* knope_h = (_Float16*)alloc((size_t)TOKENS * 2048 * 2);
  _Float16* vT_h    = (_Float16*)alloc((size_t)2048 * TOKENS * 2);
  _Float16* krope_h = (_Float16*)alloc((size_t)TOKENS * DR * 2);
  _Float16* attn_h  = (_Float16*)alloc((size_t)TOKENS * 2048 * 2);

  // ---- one fused conversion dispatch ----
  CvtSegs cs;
  const float* srcs[8] = {x, wq_down, wq_up, wq_rope, wkv_down, wk_rope, wkv_up, wo};
  _Float16* dsts[8] = {x_h, wqd_h, wquqr_h, wquqr_h + (size_t)2048 * QR,
                       wkvdr_h, wkvdr_h + (size_t)512 * DIM, wkvu_h, wo_h};
  const size_t ns[8] = {(size_t)TOKENS * DIM, (size_t)QR * DIM, (size_t)2048 * QR,
                        (size_t)1024 * QR, (size_t)KVR * DIM, (size_t)DR * DIM,
                        (size_t)NH * 256 * KVR, (size_t)DIM * NH * DV};
  int cum = 0;
  for (int i = 0; i < 8; ++i) {
    cs.src[i] = srcs[i];
    cs.dst[i] = dsts[i];
    cs.n4[i] = (int)(ns[i] / 4);
    cs.cum[i] = cum;
    cum += (cs.n4[i] + 255) / 256;
  }
  cs.cum[8] = cum;
  cvt_all<<<dim3(cum), 256, 0, stream>>>(cs);

  auto gx = [](int n) { return (unsigned)((n + 127) / 128); };
  const unsigned gm = TOKENS / 128;

  // q path: x -> qc (N=1536)
  gemm_nt<0><<<dim3(gx(QR), gm), 256, 0, stream>>>(x_h, wqd_h, qc_h, nullptr, TOKENS, QR, DIM);
  rmsnorm_ip<QR><<<dim3(TOKENS), 256, 0, stream>>>(qc_h, q_norm_w);
  // kv path fused with rope-key: x -> kvc | krope (N=576)
  gemm_nt<4><<<dim3(gx(576), gm), 256, 0, stream>>>(x_h, wkvdr_h, kvc_h, krope_h, TOKENS, 576, DIM);
  rmsnorm_ip<KVR><<<dim3(TOKENS), 256, 0, stream>>>(kvc_h, kv_norm_w);
  rope_k<<<dim3(TOKENS * 32 / 256), 256, 0, stream>>>(krope_h);
  // q up fused: qc -> qnope | qpe (N=3072)
  gemm_nt<3><<<dim3(gx(3072), gm), 256, 0, stream>>>(qc_h, wquqr_h, qnope_h, qpe_h, TOKENS, 3072, QR);
  rope_q<<<dim3(TOKENS * NH * 32 / 256), 256, 0, stream>>>(qpe_h);
  // kv up-projection, split epilogue: k_nope natural + V transposed
  gemm_nt<2><<<dim3(gx(4096), gm), 256, 0, stream>>>(kvc_h, wkvu_h, knope_h, vT_h, TOKENS, 4096, KVR);
  // attention
  mla_attn<<<dim3(512), 256, 0, stream>>>(qnope_h, qpe_h, knope_h, krope_h, vT_h, attn_h);
  // output projection (fp32 out)
  gemm_nt<1><<<dim3(gx(DIM), gm), 256, 0, stream>>>(attn_h, wo_h, out, nullptr, TOKENS, DIM, NH * DV);
}